// Round 4
// baseline (1803.775 us; speedup 1.0000x reference)
//
#include <hip/hip_runtime.h>
#include <stdint.h>

typedef unsigned short ushort_t;
typedef unsigned long long ull_t;
typedef __attribute__((ext_vector_type(8))) short bf16x8;
typedef __attribute__((ext_vector_type(8))) unsigned short u16x8;
typedef __attribute__((ext_vector_type(4))) unsigned short u16x4;
typedef __attribute__((ext_vector_type(4))) float f32x4;
typedef __attribute__((ext_vector_type(4))) unsigned u32x4;

#define DEV static __device__ __forceinline__
#define SCOPE_AGENT __HIP_MEMORY_SCOPE_AGENT

DEV unsigned short f2bf(float f) {           // fp32 -> bf16 RNE
  unsigned u = __float_as_uint(f);
  u += 0x7FFFu + ((u >> 16) & 1u);
  return (unsigned short)(u >> 16);
}
DEV float bf2f(unsigned short h) { return __uint_as_float(((unsigned)h) << 16); }
DEV float fast_rcp(float x) { return __builtin_amdgcn_rcpf(x); }
DEV float fast_tanh(float x) { float e = __expf(2.f * x); return (e - 1.f) * fast_rcp(e + 1.f); }
DEV float fast_sigm(float x) { return fast_rcp(1.f + __expf(-x)); }

DEV float wave_sum(float v) {
#pragma unroll
  for (int d = 32; d > 0; d >>= 1) v += __shfl_xor(v, d, 64);
  return v;
}
DEV float wave_max(float v) {
#pragma unroll
  for (int d = 32; d > 0; d >>= 1) v = fmaxf(v, __shfl_xor(v, d, 64));
  return v;
}

DEV void async_g2l(const void* g, void* l) {   // 16B global -> LDS (dest = uniform base + lane*16)
  __builtin_amdgcn_global_load_lds((const __attribute__((address_space(1))) void*)g,
                                   (__attribute__((address_space(3))) void*)l, 16, 0, 0);
}

// ---- scoped communication helpers ----
DEV unsigned ld_flag(unsigned* p) { return __hip_atomic_load(p, __ATOMIC_RELAXED, SCOPE_AGENT); }
DEV void st_flag(unsigned* p, unsigned v) { __hip_atomic_store(p, v, __ATOMIC_RELAXED, SCOPE_AGENT); }
DEV void st_u64(ull_t* p, ull_t v) { __hip_atomic_store(p, v, __ATOMIC_RELAXED, SCOPE_AGENT); }
DEV void release_fence() { __builtin_amdgcn_s_waitcnt(0); }   // drain vm+lgkm: prior stores acked

// coherent (L1/L2-bypass) COALESCING plain loads - unlike per-lane atomics, a wave's
// lanes reading one 64B segment collapse into a single fabric transaction.
DEV u32x4 ld_coh16(const void* p) {
  u32x4 v;
  asm volatile("global_load_dwordx4 %0, %1, off sc0 sc1" : "=v"(v) : "v"(p));
  return v;
}
DEV unsigned ld_coh4(const unsigned* p) {
  unsigned v;
  asm volatile("global_load_dword %0, %1, off sc0 sc1" : "=v"(v) : "v"(p));
  return v;
}
DEV void wait_vm0() { asm volatile("s_waitcnt vmcnt(0)" ::: "memory"); }

// ---------------- fp32 -> bf16 bulk convert (float4 at a time) ----------------
__global__ void k_f2bf(const float* __restrict__ in, ushort_t* __restrict__ out, int n4) {
  int i = blockIdx.x * blockDim.x + threadIdx.x;
  int st = gridDim.x * blockDim.x;
  for (; i < n4; i += st) {
    f32x4 v = *(const f32x4*)(in + (size_t)i * 4);
    u16x4 o;
    o[0] = f2bf(v[0]); o[1] = f2bf(v[1]); o[2] = f2bf(v[2]); o[3] = f2bf(v[3]);
    *(u16x4*)(out + (size_t)i * 4) = o;
  }
}

// ---------------- init GEMM (fp32 vector): P[m,r] = A'[m,:]·W4[r,512+:] (bf16 out) ----------------
__global__ __launch_bounds__(256) void k_initP(
    const float* __restrict__ w, const float* __restrict__ sent,
    const float* __restrict__ W4, ushort_t* __restrict__ P, float* __restrict__ sp)
{
  __shared__ float As2[16 * 68];
  __shared__ float Bs2[16 * 68];
  const int tid = threadIdx.x;
  const int m0 = blockIdx.x * 64, n0 = blockIdx.y * 64;
  const int tm = tid & 15, tn = tid >> 4;
  const bool sent_half = (m0 >= 4096);
  float acc[4][4];
#pragma unroll
  for (int i = 0; i < 4; i++)
#pragma unroll
    for (int j = 0; j < 4; j++) acc[i][j] = 0.f;

  for (int k0 = 0; k0 < 512; k0 += 16) {
#pragma unroll
    for (int i = 0; i < 4; i++) {
      int idx = i * 256 + tid;
      int r = idx >> 4, kk = idx & 15;
      int m = m0 + r;
      float va = 0.f;
      if (m < 4096) va = w[(size_t)m * 512 + k0 + kk];
      else if (m < 4128) va = sent[(m - 4096) * 512 + k0 + kk];
      As2[kk * 68 + r] = va;
      Bs2[kk * 68 + r] = W4[(size_t)(n0 + r) * 1024 + (sent_half ? 0 : 512) + k0 + kk];
    }
    __syncthreads();
#pragma unroll
    for (int k = 0; k < 16; k++) {
      f32x4 av = *(const f32x4*)&As2[k * 68 + tm * 4];
      f32x4 bv = *(const f32x4*)&Bs2[k * 68 + tn * 4];
#pragma unroll
      for (int i = 0; i < 4; i++)
#pragma unroll
        for (int j = 0; j < 4; j++) acc[i][j] = fmaf(av[i], bv[j], acc[i][j]);
    }
    __syncthreads();
  }
#pragma unroll
  for (int i = 0; i < 4; i++) {
    int m = m0 + tm * 4 + i;
    if (m >= 4128) continue;
#pragma unroll
    for (int j = 0; j < 4; j++) {
      int n = n0 + tn * 4 + j;
      if (m < 4096) P[(size_t)m * 512 + n] = f2bf(acc[i][j]);
      else sp[(m - 4096) * 512 + n] = acc[i][j];
    }
  }
}

// ---------------- persistent recurrence ----------------
// Blocks 0..15  : gate blocks - each owns 32 h-dims (128 gate rows), weights in registers.
// Blocks 16..47 : attention blocks - one per batch; word read as bf16 from global (LLC-resident).
// Blocks 48..255: W_out fp32->bf16 converters (run in recurrence's idle shadow, no sync).
// Handoffs per step: x (attn->gates, xflag[32]) and h (gates->all, hflag[16]).
// Data publishes: per-lane 8B agent-scope atomics (round-1-proven protocol).
// Flag POLLS: wave-coalesced plain sc0+sc1 loads (1 fabric txn/poll vs 16-32 for atomic
// per-lane polls) - per-lane atomic polls hammered 2-3 LLC lines with ~1.3K serialized
// transactions per poll iteration, which dominated the step time.
struct GateS {
  ushort_t XH[32 * 520];      // staged [batch][k] bf16, padded
  float gates[32 * 132];      // [batch][128 gate rows + pad]
  float bias[128];
  float cstate[1024];         // [batch][32 h-dims]
  ushort_t hs16[1024];        // [batch][32] bf16
};
struct AttnS {
  float hs[512];
  float sps[512];
  float sc[128];
  float attw[128];
  float xpart[8 * 520];
  ushort_t xs16[512];
};

__global__ __launch_bounds__(512) void k_recur(
    const float* __restrict__ W2, const float* __restrict__ W_ih, const float* __restrict__ W_hh,
    const float* __restrict__ b_ih, const float* __restrict__ b_hh,
    const ushort_t* __restrict__ w_bf, const ushort_t* __restrict__ P, const float* __restrict__ sp,
    unsigned* hflag, unsigned* xflag, ull_t* hbuf, ull_t* xbuf,
    ull_t* __restrict__ h_A, float* __restrict__ h_fin,
    const float* __restrict__ W_out, ushort_t* __restrict__ Wout_bf)
{
  __shared__ union { GateS g; AttnS a; } sm;
  const int bid = blockIdx.x, tid = threadIdx.x;
  const int wv = tid >> 6, lane = tid & 63;

  if (bid >= 48) {
    // ================= W_out converter (concurrent with recurrence) =================
    int idx = (bid - 48) * 512 + tid;
    const int stp = (256 - 48) * 512;
    for (; idx < 4096000; idx += stp) {
      f32x4 v = *(const f32x4*)(W_out + (size_t)idx * 4);
      u16x4 o;
      o[0] = f2bf(v[0]); o[1] = f2bf(v[1]); o[2] = f2bf(v[2]); o[3] = f2bf(v[3]);
      *(u16x4*)(Wout_bf + (size_t)idx * 4) = o;
    }
    return;
  }

  // coalesced poll: all 64 lanes of wave 0 read flags[lane & (N-1)] (one 64-128B segment
  // -> 1-2 fabric transactions), __all() across lanes decides readiness.
#define POLL16(FLAGS, TVAL)                                               \
    for (;;) {                                                            \
      unsigned fv_ = ld_coh4(&(FLAGS)[lane & 15]);                        \
      wait_vm0();                                                         \
      if (__all((int)(fv_ >= (unsigned)(TVAL)))) break;                   \
      __builtin_amdgcn_s_sleep(4);                                        \
    }
#define POLL32(FLAGS, TVAL)                                               \
    for (;;) {                                                            \
      unsigned fv_ = ld_coh4(&(FLAGS)[lane & 31]);                        \
      wait_vm0();                                                         \
      if (__all((int)(fv_ >= (unsigned)(TVAL)))) break;                   \
      __builtin_amdgcn_s_sleep(4);                                        \
    }

  if (bid < 16) {
    // ================= gate block =================
    const int ln = lane & 15, quad = lane >> 4;
    const int grow = (wv >> 1) * 512 + (bid << 5) + ((wv & 1) << 4) + ln;
    sm.g.cstate[tid] = 0.f;
    sm.g.cstate[tid + 512] = 0.f;
    if (tid < 128) {
      int gr = (tid >> 5) * 512 + (bid << 5) + (tid & 31);
      sm.g.bias[tid] = b_ih[gr] + b_hh[gr];
    }
    bf16x8 fih[16], fhh[16];
#pragma unroll
    for (int ks = 0; ks < 16; ks++) {
      const float* pi = W_ih + (size_t)grow * 512 + ks * 32 + quad * 8;
      const float* ph = W_hh + (size_t)grow * 512 + ks * 32 + quad * 8;
#pragma unroll
      for (int j = 0; j < 8; j++) {
        fih[ks][j] = (short)f2bf(pi[j]);
        fhh[ks][j] = (short)f2bf(ph[j]);
      }
    }
    __syncthreads();

#define STAGE_XH(SRC)                                                         \
    {                                                                         \
      const char* src_ = (const char*)(SRC);                                  \
      u32x4 r0 = ld_coh16(src_ + (tid << 4));                                 \
      u32x4 r1 = ld_coh16(src_ + ((512 + tid) << 4));                         \
      u32x4 r2 = ld_coh16(src_ + ((1024 + tid) << 4));                        \
      u32x4 r3 = ld_coh16(src_ + ((1536 + tid) << 4));                        \
      wait_vm0();                                                             \
      int c1 = 512 + tid, c2 = 1024 + tid, c3 = 1536 + tid;                   \
      *(u32x4*)&sm.g.XH[(tid >> 6) * 520 + (tid & 63) * 8] = r0;              \
      *(u32x4*)&sm.g.XH[(c1 >> 6) * 520 + (c1 & 63) * 8] = r1;                \
      *(u32x4*)&sm.g.XH[(c2 >> 6) * 520 + (c2 & 63) * 8] = r2;                \
      *(u32x4*)&sm.g.XH[(c3 >> 6) * 520 + (c3 & 63) * 8] = r3;                \
    }

#define GATE_MFMA(FW)                                                         \
    _Pragma("unroll")                                                         \
    for (int ks = 0; ks < 16; ks++) {                                         \
      bf16x8 a0 = *(const bf16x8*)&sm.g.XH[ln * 520 + ks * 32 + quad * 8];    \
      bf16x8 a1 = *(const bf16x8*)&sm.g.XH[(16 + ln) * 520 + ks * 32 + quad * 8]; \
      acc0 = __builtin_amdgcn_mfma_f32_16x16x32_bf16(a0, FW[ks], acc0, 0, 0, 0);  \
      acc1 = __builtin_amdgcn_mfma_f32_16x16x32_bf16(a1, FW[ks], acc1, 0, 0, 0);  \
    }

    for (int t = 0; t < 64; t++) {
      if (t > 0 && wv == 0) { POLL16(hflag, t) }
      __syncthreads();
      // stage h[t-1] (parity-buffered, t=0 reads zeroed parity 1)
      STAGE_XH(hbuf + ((t + 1) & 1) * 4096);
      __syncthreads();
      f32x4 acc0 = {0.f, 0.f, 0.f, 0.f}, acc1 = {0.f, 0.f, 0.f, 0.f};
      GATE_MFMA(fhh)                      // W_hh half - overlaps attention's compute
      if (wv == 0) { POLL32(xflag, t + 1) }
      __syncthreads();                    // also guards XH reuse (hh reads done)
      STAGE_XH(xbuf);
      __syncthreads();
      GATE_MFMA(fih)                      // W_ih half
      {
        float bb = sm.g.bias[wv * 16 + ln];
#pragma unroll
        for (int reg = 0; reg < 4; reg++) {
          sm.g.gates[(quad * 4 + reg) * 132 + wv * 16 + ln] = acc0[reg] + bb;
          sm.g.gates[(16 + quad * 4 + reg) * 132 + wv * 16 + ln] = acc1[reg] + bb;
        }
      }
      __syncthreads();
#pragma unroll
      for (int i = 0; i < 2; i++) {
        int e = i * 512 + tid;
        int b = e >> 5, hd = e & 31;
        float gi = sm.g.gates[b * 132 + hd];
        float gf = sm.g.gates[b * 132 + 32 + hd];
        float gg = sm.g.gates[b * 132 + 64 + hd];
        float go = sm.g.gates[b * 132 + 96 + hd];
        float cold = sm.g.cstate[e];
        float cn = fast_sigm(gf) * cold + fast_sigm(gi) * fast_tanh(gg);
        float hn = fast_sigm(go) * fast_tanh(cn);
        sm.g.cstate[e] = cn;
        sm.g.hs16[e] = f2bf(hn);
        if (t == 63) h_fin[b * 512 + (bid << 5) + hd] = hn;
      }
      __syncthreads();
      if (tid < 256) {
        int bb = tid >> 3, j = tid & 7;
        ull_t v = *(const ull_t*)&sm.g.hs16[(bb << 5) + (j << 2)];
        st_u64(&hbuf[(t & 1) * 4096 + (bb << 7) + (bid << 3) + j], v);   // h[t], parity-buffered
        h_A[(size_t)((bb << 6) + t) * 128 + (bid << 3) + j] = v;         // GEMM A row (plain store)
        release_fence();
      }
      __syncthreads();
      if (tid == 0) st_flag(&hflag[bid], (unsigned)(t + 1));
    }
#undef STAGE_XH
#undef GATE_MFMA
  } else {
    // ================= attention block (batch b) =================
    const int b = bid - 16;
    float w2v[8];
#pragma unroll
    for (int j = 0; j < 8; j++) w2v[j] = W2[lane * 8 + j];
    sm.a.sps[tid] = sp[b * 512 + tid];
    __syncthreads();

    for (int t = 0; t < 64; t++) {
      if (t > 0 && wv == 0) { POLL16(hflag, t) }
      __syncthreads();
      if (tid < 64) {   // stage h[t-1] -> LDS (coalesced coherent 16B loads)
        u32x4 hv = ld_coh16((const char*)hbuf + (((t + 1) & 1) << 15) + (b << 10) + (tid << 4));
        wait_vm0();
#pragma unroll
        for (int j = 0; j < 4; j++) {
          sm.a.hs[tid * 8 + 2 * j]     = bf2f((ushort_t)(hv[j] & 0xffffu));
          sm.a.hs[tid * 8 + 2 * j + 1] = bf2f((ushort_t)(hv[j] >> 16));
        }
      }
      __syncthreads();
      // scores: wave wv does s = wv*16 .. wv*16+15 (word from global bf16, LLC-resident)
      float hf[8];
#pragma unroll
      for (int j = 0; j < 8; j++) hf[j] = sm.a.hs[lane * 8 + j];
#pragma unroll 2
      for (int i = 0; i < 16; i++) {
        int s = (wv << 4) + i;
        u16x8 wvv = *(const u16x8*)(w_bf + ((size_t)((b << 7) + s) << 9) + (lane << 3));
        float acc = 0.f;
#pragma unroll
        for (int j = 0; j < 8; j++) {
          float v = bf2f(wvv[j]) + hf[j];
          float e = __expf(v + v);
          acc = fmaf((e - 1.f) * fast_rcp(e + 1.f), w2v[j], acc);
        }
        acc = wave_sum(acc);
        if (lane == 0) sm.a.sc[s] = acc;
      }
      __syncthreads();
      if (wv == 0) {   // softmax (wave 0)
        float a0 = sm.a.sc[lane], a1 = sm.a.sc[lane + 64];
        float m = wave_max(fmaxf(a0, a1));
        float e0 = __expf(a0 - m), e1 = __expf(a1 - m);
        float inv = fast_rcp(wave_sum(e0 + e1));
        sm.a.attw[lane] = e0 * inv;
        sm.a.attw[lane + 64] = e1 * inv;
      }
      __syncthreads();
      // x = tanh(sp + attn·P): wave wv handles s in [wv*16, wv*16+16), lane owns r = lane*8..+8
      {
        f32x4 xacc0 = {0.f, 0.f, 0.f, 0.f}, xacc1 = {0.f, 0.f, 0.f, 0.f};
        const ushort_t* Pb = P + (((size_t)b * 128 + (wv << 4)) << 9) + lane * 8;
#pragma unroll 4
        for (int i = 0; i < 16; i++) {
          float aw = sm.a.attw[(wv << 4) + i];
          u16x8 pv = *(const u16x8*)(Pb + ((size_t)i << 9));
#pragma unroll
          for (int j = 0; j < 4; j++) xacc0[j] = fmaf(aw, bf2f(pv[j]), xacc0[j]);
#pragma unroll
          for (int j = 0; j < 4; j++) xacc1[j] = fmaf(aw, bf2f(pv[4 + j]), xacc1[j]);
        }
        *(f32x4*)&sm.a.xpart[wv * 520 + lane * 8] = xacc0;
        *(f32x4*)&sm.a.xpart[wv * 520 + lane * 8 + 4] = xacc1;
      }
      __syncthreads();
      {
        float xv = sm.a.sps[tid];
#pragma unroll
        for (int g = 0; g < 8; g++) xv += sm.a.xpart[g * 520 + tid];
        sm.a.xs16[tid] = f2bf(fast_tanh(xv));
      }
      __syncthreads();
      if (tid < 128) {
        ull_t v = *(const ull_t*)&sm.a.xs16[tid << 2];
        st_u64(&xbuf[(b << 7) + tid], v);
        release_fence();
      }
      __syncthreads();
      if (tid == 0) st_flag(&xflag[b], (unsigned)(t + 1));
    }
  }
#undef POLL16
#undef POLL32
}

// ---------------- big GEMM: C[2048,32000] = h_A[2048,512] x W_out_bf[32000,512]^T + b ----------------
__global__ __launch_bounds__(256) void k_gemm(
    const ushort_t* __restrict__ A, const ushort_t* __restrict__ Bw,
    const float* __restrict__ bias, float* __restrict__ C)
{
  __shared__ ushort_t As[128 * 64];
  __shared__ ushort_t Bs[128 * 64];
  const int tid = threadIdx.x;
  const int wave = tid >> 6, lane = tid & 63;
  const int ln = lane & 15, quad = lane >> 4;
  const int bm = blockIdx.x & 15, bn = blockIdx.x >> 4;
  const int wm = wave & 1, wn = wave >> 1;

  f32x4 acc[4][4];
#pragma unroll
  for (int i = 0; i < 4; i++)
#pragma unroll
    for (int j = 0; j < 4; j++) { acc[i][j][0] = 0.f; acc[i][j][1] = 0.f; acc[i][j][2] = 0.f; acc[i][j][3] = 0.f; }

  for (int kt = 0; kt < 8; kt++) {
    const int k0 = kt * 64;
#pragma unroll
    for (int i = 0; i < 4; i++) {
      int s = i * 256 + tid;
      int r = s >> 3, c = s & 7;
      int cs = c ^ (r & 7);
      async_g2l(A + ((size_t)(bm * 128 + r) << 9) + k0 + (cs << 3), &As[s << 3]);
    }
#pragma unroll
    for (int i = 0; i < 4; i++) {
      int s = i * 256 + tid;
      int r = s >> 3, c = s & 7;
      int cs = c ^ (r & 7);
      async_g2l(Bw + ((size_t)(bn * 128 + r) << 9) + k0 + (cs << 3), &Bs[s << 3]);
    }
    __syncthreads();
#pragma unroll
    for (int ks = 0; ks < 2; ks++) {
      bf16x8 af[4], bfr[4];
      int cc = ks * 4 + quad;
#pragma unroll
      for (int f = 0; f < 4; f++) {
        int ra = wm * 64 + f * 16 + ln;
        af[f] = *(const bf16x8*)&As[((ra << 3) + (cc ^ (ra & 7))) << 3];
        int rb = wn * 64 + f * 16 + ln;
        bfr[f] = *(const bf16x8*)&Bs[((rb << 3) + (cc ^ (rb & 7))) << 3];
      }
#pragma unroll
      for (int mf = 0; mf < 4; mf++)
#pragma unroll
        for (int nf = 0; nf < 4; nf++)
          acc[mf][nf] = __builtin_amdgcn_mfma_f32_16x16x32_bf16(af[mf], bfr[nf], acc[mf][nf], 0, 0, 0);
    }
    __syncthreads();
  }
#pragma unroll
  for (int nf = 0; nf < 4; nf++) {
    int n = bn * 128 + wn * 64 + nf * 16 + ln;
    float bv = bias[n];
#pragma unroll
    for (int mf = 0; mf < 4; mf++) {
      int mbase = bm * 128 + wm * 64 + mf * 16 + (quad << 2);
#pragma unroll
      for (int r = 0; r < 4; r++)
        C[(size_t)(mbase + r) * 32000 + n] = acc[mf][nf][r] + bv;
    }
  }
}

// ---------------- launch ----------------
extern "C" void kernel_launch(void* const* d_in, const int* in_sizes, int n_in,
                              void* d_out, int out_size, void* d_ws, size_t ws_size,
                              hipStream_t stream) {
  const float* word  = (const float*)d_in[0];
  const float* sent  = (const float*)d_in[1];
  const float* W2    = (const float*)d_in[2];
  const float* W4    = (const float*)d_in[3];
  const float* W_ih  = (const float*)d_in[4];
  const float* W_hh  = (const float*)d_in[5];
  const float* b_ih  = (const float*)d_in[6];
  const float* b_hh  = (const float*)d_in[7];
  const float* W_out = (const float*)d_in[8];
  const float* b_out = (const float*)d_in[9];
  float* out = (float*)d_out;

  char* ws = (char*)d_ws;
  unsigned* hflag   = (unsigned*)(ws + 0);          // [16]
  unsigned* xflag   = (unsigned*)(ws + 512);        // [32]
  ull_t*    hbuf    = (ull_t*)(ws + 1024);          // 2 x [32][128] u64 bf16 (parity)
  ull_t*    xbuf    = (ull_t*)(ws + 66560);         // [32][128] u64 bf16
  float*    sp      = (float*)(ws + 99328);         // [32][512] fp32
  ushort_t* P       = (ushort_t*)(ws + 164864);     // [32][128][512] bf16
  ushort_t* w_bf    = (ushort_t*)(ws + 4359168);    // [32][128][512] bf16
  ull_t*    h_A     = (ull_t*)(ws + 8553472);       // [2048][512] bf16 (m = b*64+t)
  ushort_t* Wout_bf = (ushort_t*)(ws + 10650624);   // [32000][512] bf16 -> ends 43,418,624
  float* h_fin = out + 65536000;

  hipMemsetAsync(ws, 0, 66560, stream);             // zero flags + both h parity buffers

  k_f2bf<<<512, 256, 0, stream>>>(word, w_bf, 2097152 / 4);
  k_initP<<<dim3(65, 8), 256, 0, stream>>>(word, sent, W4, P, sp);
  k_recur<<<256, 512, 0, stream>>>(W2, W_ih, W_hh, b_ih, b_hh, w_bf, P, sp,
                                   hflag, xflag, hbuf, xbuf, h_A, h_fin, W_out, Wout_bf);
  k_gemm<<<4000, 256, 0, stream>>>((const ushort_t*)h_A, Wout_bf, b_out, out);
}

// Round 5
// 1578.420 us; speedup vs baseline: 1.1428x; 1.1428x over previous
//
#include <hip/hip_runtime.h>
#include <stdint.h>

typedef unsigned short ushort_t;
typedef unsigned long long ull_t;
typedef __attribute__((ext_vector_type(8))) short bf16x8;
typedef __attribute__((ext_vector_type(8))) unsigned short u16x8;
typedef __attribute__((ext_vector_type(4))) unsigned short u16x4;
typedef __attribute__((ext_vector_type(4))) float f32x4;

#define DEV static __device__ __forceinline__
#define SCOPE_AGENT __HIP_MEMORY_SCOPE_AGENT

DEV unsigned short f2bf(float f) {           // fp32 -> bf16 RNE
  unsigned u = __float_as_uint(f);
  u += 0x7FFFu + ((u >> 16) & 1u);
  return (unsigned short)(u >> 16);
}
DEV float bf2f(unsigned short h) { return __uint_as_float(((unsigned)h) << 16); }
DEV float fast_rcp(float x) { return __builtin_amdgcn_rcpf(x); }
DEV float fast_tanh(float x) { float e = __expf(2.f * x); return (e - 1.f) * fast_rcp(e + 1.f); }
DEV float fast_sigm(float x) { return fast_rcp(1.f + __expf(-x)); }

DEV float wave_sum(float v) {
#pragma unroll
  for (int d = 32; d > 0; d >>= 1) v += __shfl_xor(v, d, 64);
  return v;
}
DEV float wave_max(float v) {
#pragma unroll
  for (int d = 32; d > 0; d >>= 1) v = fmaxf(v, __shfl_xor(v, d, 64));
  return v;
}

DEV void async_g2l(const void* g, void* l) {   // 16B global -> LDS (dest = uniform base + lane*16)
  __builtin_amdgcn_global_load_lds((const __attribute__((address_space(1))) void*)g,
                                   (__attribute__((address_space(3))) void*)l, 16, 0, 0);
}

// ---- scoped-atomic communication helpers (round-0-proven protocol) ----
DEV unsigned ld_flag(unsigned* p) { return __hip_atomic_load(p, __ATOMIC_RELAXED, SCOPE_AGENT); }
DEV void st_flag(unsigned* p, unsigned v) { __hip_atomic_store(p, v, __ATOMIC_RELAXED, SCOPE_AGENT); }
DEV ull_t ld_u64(ull_t* p) { return __hip_atomic_load(p, __ATOMIC_RELAXED, SCOPE_AGENT); }
DEV void st_u64(ull_t* p, ull_t v) { __hip_atomic_store(p, v, __ATOMIC_RELAXED, SCOPE_AGENT); }
DEV void release_fence() { __builtin_amdgcn_s_waitcnt(0); }   // drain vm+lgkm: prior stores visible

// ---------------- fp32 -> bf16 bulk convert with scale (float4 at a time) ----------------
__global__ void k_f2bf(const float* __restrict__ in, ushort_t* __restrict__ out, int n4, float scale) {
  int i = blockIdx.x * blockDim.x + threadIdx.x;
  int st = gridDim.x * blockDim.x;
  for (; i < n4; i += st) {
    f32x4 v = *(const f32x4*)(in + (size_t)i * 4);
    u16x4 o;
    o[0] = f2bf(v[0] * scale); o[1] = f2bf(v[1] * scale);
    o[2] = f2bf(v[2] * scale); o[3] = f2bf(v[3] * scale);
    *(u16x4*)(out + (size_t)i * 4) = o;
  }
}

// ---------------- init GEMM (fp32 vector): P[m,r] = A'[m,:]·W4[r,512+:] (bf16 out) ----------------
__global__ __launch_bounds__(256) void k_initP(
    const float* __restrict__ w, const float* __restrict__ sent,
    const float* __restrict__ W4, ushort_t* __restrict__ P, float* __restrict__ sp)
{
  __shared__ float As2[16 * 68];
  __shared__ float Bs2[16 * 68];
  const int tid = threadIdx.x;
  const int m0 = blockIdx.x * 64, n0 = blockIdx.y * 64;
  const int tm = tid & 15, tn = tid >> 4;
  const bool sent_half = (m0 >= 4096);
  float acc[4][4];
#pragma unroll
  for (int i = 0; i < 4; i++)
#pragma unroll
    for (int j = 0; j < 4; j++) acc[i][j] = 0.f;

  for (int k0 = 0; k0 < 512; k0 += 16) {
#pragma unroll
    for (int i = 0; i < 4; i++) {
      int idx = i * 256 + tid;
      int r = idx >> 4, kk = idx & 15;
      int m = m0 + r;
      float va = 0.f;
      if (m < 4096) va = w[(size_t)m * 512 + k0 + kk];
      else if (m < 4128) va = sent[(m - 4096) * 512 + k0 + kk];
      As2[kk * 68 + r] = va;
      Bs2[kk * 68 + r] = W4[(size_t)(n0 + r) * 1024 + (sent_half ? 0 : 512) + k0 + kk];
    }
    __syncthreads();
#pragma unroll
    for (int k = 0; k < 16; k++) {
      f32x4 av = *(const f32x4*)&As2[k * 68 + tm * 4];
      f32x4 bv = *(const f32x4*)&Bs2[k * 68 + tn * 4];
#pragma unroll
      for (int i = 0; i < 4; i++)
#pragma unroll
        for (int j = 0; j < 4; j++) acc[i][j] = fmaf(av[i], bv[j], acc[i][j]);
    }
    __syncthreads();
  }
#pragma unroll
  for (int i = 0; i < 4; i++) {
    int m = m0 + tm * 4 + i;
    if (m >= 4128) continue;
#pragma unroll
    for (int j = 0; j < 4; j++) {
      int n = n0 + tn * 4 + j;
      if (m < 4096) P[(size_t)m * 512 + n] = f2bf(acc[i][j]);
      else sp[(m - 4096) * 512 + n] = acc[i][j];
    }
  }
}

// ---------------- persistent recurrence: 160 blocks x 512 threads (round-0 layout) ----------------
// Blocks 0..127  : gate blocks — own 4 h-rows (16 gate rows), weights persistent in registers.
// Blocks 128..159: attention blocks — one per batch, scores+softmax+x fully block-local.
// This round: attention score phase thinned — tanh-dot via 1-2/(1+e^{2x}) identity
// (w_bf pre-scaled by 2.0, exact in bf16; Sum(W2) hoisted) and the 16 sequential
// wave_sum bpermute chains replaced by one LDS partial-reduce pass.
struct GateS {
  ushort_t XHx[32 * 520];     // staged [batch][k] bf16, padded
  float gredf[8 * 512];       // per-wave MFMA partials
  float gates[32 * 17];
  float bias[16];
  float cstate[128];
  ushort_t hs16[128];
};
struct AttnS {
  float hs[512];              // 2*h[t-1] (scores-only)
  float sps[512];
  float scp[128 * 68];        // per-lane score partials, padded rows
  float scp4[512];            // 4-per-s reduced partials
  float attw[128];
  float xpart[8 * 520];
  ushort_t xs16[512];
};

__global__ __launch_bounds__(512) void k_recur(
    const float* __restrict__ W2, const float* __restrict__ W_ih, const float* __restrict__ W_hh,
    const float* __restrict__ b_ih, const float* __restrict__ b_hh,
    const ushort_t* __restrict__ w_bf, const ushort_t* __restrict__ P, const float* __restrict__ sp,
    unsigned* hflag, unsigned* xflag, ull_t* hbuf, ull_t* xbuf,
    ull_t* __restrict__ h_A, float* __restrict__ h_fin)
{
  __shared__ union { GateS g; AttnS a; } sm;
  const int bid = blockIdx.x, tid = threadIdx.x;
  const int wv = tid >> 6, lane = tid & 63;

  if (bid < 128) {
    // ================= gate block =================
    const int n16 = lane & 15, quad = lane >> 4;
    const int grow = (n16 >> 2) * 512 + (bid << 2) + (n16 & 3);
    if (tid < 128) sm.g.cstate[tid] = 0.f;
    if (tid < 16) {
      int gr = (tid >> 2) * 512 + (bid << 2) + (tid & 3);
      sm.g.bias[tid] = b_ih[gr] + b_hh[gr];
    }
    bf16x8 fih[2], fhh[2];
#pragma unroll
    for (int ks = 0; ks < 2; ks++) {
      int kk = (wv * 2 + ks) * 32 + quad * 8;
      const float* pi = W_ih + (size_t)grow * 512 + kk;
      const float* ph = W_hh + (size_t)grow * 512 + kk;
#pragma unroll
      for (int j = 0; j < 8; j++) {
        fih[ks][j] = (short)f2bf(pi[j]);
        fhh[ks][j] = (short)f2bf(ph[j]);
      }
    }
    __syncthreads();

    for (int t = 0; t < 64; t++) {
      // wait h[t-1] published (t=0: hbuf parity 1 is zeroed h0)
      if (t > 0 && tid < 128) {
        while (ld_flag(&hflag[tid]) < (unsigned)t) __builtin_amdgcn_s_sleep(2);
      }
      __syncthreads();
      // stage h[t-1] -> LDS
      ull_t* hsrc = hbuf + ((t + 1) & 1) * 4096;
#pragma unroll
      for (int i = 0; i < 8; i++) {
        int fl = i * 512 + tid;
        ull_t v = ld_u64(&hsrc[fl]);
        *(ull_t*)&sm.g.XHx[(fl >> 7) * 520 + (fl & 127) * 4] = v;
      }
      __syncthreads();
      f32x4 acc0 = {0.f, 0.f, 0.f, 0.f}, acc1 = {0.f, 0.f, 0.f, 0.f};
#pragma unroll
      for (int ks = 0; ks < 2; ks++) {      // W_hh half — overlaps attention's compute
        int kk = (wv * 2 + ks) * 32 + quad * 8;
        bf16x8 a0 = *(const bf16x8*)&sm.g.XHx[n16 * 520 + kk];
        bf16x8 a1 = *(const bf16x8*)&sm.g.XHx[(16 + n16) * 520 + kk];
        acc0 = __builtin_amdgcn_mfma_f32_16x16x32_bf16(a0, fhh[ks], acc0, 0, 0, 0);
        acc1 = __builtin_amdgcn_mfma_f32_16x16x32_bf16(a1, fhh[ks], acc1, 0, 0, 0);
      }
      // wait x[t]
      if (tid < 32) {
        while (ld_flag(&xflag[tid]) < (unsigned)(t + 1)) __builtin_amdgcn_s_sleep(2);
      }
      __syncthreads();
#pragma unroll
      for (int i = 0; i < 8; i++) {
        int fl = i * 512 + tid;
        ull_t v = ld_u64(&xbuf[fl]);
        *(ull_t*)&sm.g.XHx[(fl >> 7) * 520 + (fl & 127) * 4] = v;
      }
      __syncthreads();
#pragma unroll
      for (int ks = 0; ks < 2; ks++) {      // W_ih half
        int kk = (wv * 2 + ks) * 32 + quad * 8;
        bf16x8 a0 = *(const bf16x8*)&sm.g.XHx[n16 * 520 + kk];
        bf16x8 a1 = *(const bf16x8*)&sm.g.XHx[(16 + n16) * 520 + kk];
        acc0 = __builtin_amdgcn_mfma_f32_16x16x32_bf16(a0, fih[ks], acc0, 0, 0, 0);
        acc1 = __builtin_amdgcn_mfma_f32_16x16x32_bf16(a1, fih[ks], acc1, 0, 0, 0);
      }
      *(f32x4*)&sm.g.gredf[wv * 512 + lane * 4] = acc0;
      *(f32x4*)&sm.g.gredf[wv * 512 + 256 + lane * 4] = acc1;
      __syncthreads();
      {
        float v = 0.f;
#pragma unroll
        for (int k = 0; k < 8; k++) v += sm.g.gredf[k * 512 + tid];
        int mt = tid >> 8, l = (tid >> 2) & 63, r = tid & 3;
        int batch = mt * 16 + ((l >> 4) << 2) + r;   // C/D: row=(lane>>4)*4+reg, col=lane&15
        int n = l & 15;
        sm.g.gates[batch * 17 + n] = v + sm.g.bias[n];
      }
      __syncthreads();
      if (tid < 128) {
        int bb = tid & 31, hr = tid >> 5;
        float gi = sm.g.gates[bb * 17 + hr];
        float gf = sm.g.gates[bb * 17 + 4 + hr];
        float gg = sm.g.gates[bb * 17 + 8 + hr];
        float go = sm.g.gates[bb * 17 + 12 + hr];
        float cold = sm.g.cstate[(bb << 2) + hr];
        float cn = fast_sigm(gf) * cold + fast_sigm(gi) * fast_tanh(gg);
        float hn = fast_sigm(go) * fast_tanh(cn);
        sm.g.cstate[(bb << 2) + hr] = cn;
        sm.g.hs16[(bb << 2) + hr] = f2bf(hn);
        if (t == 63) h_fin[bb * 512 + (bid << 2) + hr] = hn;
      }
      __syncthreads();
      if (tid < 32) {
        ull_t v = *(const ull_t*)&sm.g.hs16[tid << 2];
        st_u64(&hbuf[(t & 1) * 4096 + tid * 128 + bid], v);   // h[t], parity-buffered
        h_A[((tid << 6) + t) * 128 + bid] = v;                // GEMM A row m=b*64+t (plain store)
        release_fence();
      }
      __syncthreads();
      if (tid == 0) st_flag(&hflag[bid], (unsigned)(t + 1));
    }
  } else {
    // ================= attention block (batch b) =================
    const int b = bid - 128;
    float w2v[8];
#pragma unroll
    for (int j = 0; j < 8; j++) w2v[j] = W2[lane * 8 + j];
    float sumW2;
    {
      float sw = 0.f;
#pragma unroll
      for (int j = 0; j < 8; j++) sw += w2v[j];
      sumW2 = wave_sum(sw);              // every wave covers all 512 k
    }
    sm.a.sps[tid] = sp[b * 512 + tid];
    __syncthreads();

    for (int t = 0; t < 64; t++) {
      if (t > 0 && tid < 128) {
        while (ld_flag(&hflag[tid]) < (unsigned)t) __builtin_amdgcn_s_sleep(2);
      }
      __syncthreads();
      if (tid < 128) {                   // stage 2*h[t-1] (scores use doubled arg)
        ull_t v = ld_u64(&hbuf[((t + 1) & 1) * 4096 + b * 128 + tid]);
        sm.a.hs[tid * 4 + 0] = 2.f * bf2f((unsigned short)v);
        sm.a.hs[tid * 4 + 1] = 2.f * bf2f((unsigned short)(v >> 16));
        sm.a.hs[tid * 4 + 2] = 2.f * bf2f((unsigned short)(v >> 32));
        sm.a.hs[tid * 4 + 3] = 2.f * bf2f((unsigned short)(v >> 48));
      }
      __syncthreads();
      // scores: tanh(w+h)·W2 = SumW2 - 2*Sum W2/(1+e^{2(w+h)}); w_bf pre-scaled by 2
      float hf[8];
#pragma unroll
      for (int j = 0; j < 8; j++) hf[j] = sm.a.hs[lane * 8 + j];
#pragma unroll 4
      for (int i = 0; i < 16; i++) {
        int s = (wv << 4) + i;
        u16x8 wvv = *(const u16x8*)(w_bf + ((size_t)((b << 7) + s) << 9) + (lane << 3));
        float p = 0.f;
#pragma unroll
        for (int j = 0; j < 8; j++) {
          float v = bf2f(wvv[j]) + hf[j];        // = 2*(w+h)
          float e = __expf(v);
          p = fmaf(w2v[j], fast_rcp(1.f + e), p);
        }
        sm.a.scp[s * 68 + lane] = p;             // per-lane partial (no wave_sum chain)
      }
      __syncthreads();
      {                                          // reduce 64 partials -> 4 per s
        int s = tid >> 2, q = tid & 3;
        const float* pp = &sm.a.scp[s * 68 + q * 16];
        float r = 0.f;
#pragma unroll
        for (int m = 0; m < 16; m++) r += pp[m];
        sm.a.scp4[tid] = r;
      }
      __syncthreads();
      if (wv == 0) {   // finalize scores + softmax (wave 0)
        f32x4 p0 = *(const f32x4*)&sm.a.scp4[lane * 4];
        f32x4 p1 = *(const f32x4*)&sm.a.scp4[256 + lane * 4];
        float a0 = sumW2 - 2.f * (p0[0] + p0[1] + p0[2] + p0[3]);
        float a1 = sumW2 - 2.f * (p1[0] + p1[1] + p1[2] + p1[3]);
        float m = wave_max(fmaxf(a0, a1));
        float e0 = __expf(a0 - m), e1 = __expf(a1 - m);
        float inv = fast_rcp(wave_sum(e0 + e1));
        sm.a.attw[lane] = e0 * inv;
        sm.a.attw[lane + 64] = e1 * inv;
      }
      __syncthreads();
      // x = tanh(sp + attn·P): wave wv handles s in [wv*16, wv*16+16), lane owns r = lane*8..+8
      {
        f32x4 xacc0 = {0.f, 0.f, 0.f, 0.f}, xacc1 = {0.f, 0.f, 0.f, 0.f};
        const ushort_t* Pb = P + (((size_t)b * 128 + (wv << 4)) << 9) + lane * 8;
#pragma unroll 4
        for (int i = 0; i < 16; i++) {
          float aw = sm.a.attw[(wv << 4) + i];
          u16x8 pv = *(const u16x8*)(Pb + ((size_t)i << 9));
#pragma unroll
          for (int j = 0; j < 4; j++) xacc0[j] = fmaf(aw, bf2f(pv[j]), xacc0[j]);
#pragma unroll
          for (int j = 0; j < 4; j++) xacc1[j] = fmaf(aw, bf2f(pv[4 + j]), xacc1[j]);
        }
        *(f32x4*)&sm.a.xpart[wv * 520 + lane * 8] = xacc0;
        *(f32x4*)&sm.a.xpart[wv * 520 + lane * 8 + 4] = xacc1;
      }
      __syncthreads();
      {
        float xv = sm.a.sps[tid];
#pragma unroll
        for (int g = 0; g < 8; g++) xv += sm.a.xpart[g * 520 + tid];
        sm.a.xs16[tid] = f2bf(fast_tanh(xv));
      }
      __syncthreads();
      if (tid < 128) {
        ull_t v = *(const ull_t*)&sm.a.xs16[tid << 2];
        st_u64(&xbuf[(b << 7) + tid], v);
        release_fence();
      }
      __syncthreads();
      if (tid == 0) st_flag(&xflag[b], (unsigned)(t + 1));
    }
  }
}

// ---------------- big GEMM: C[2048,32000] = h_A[2048,512] x W_out_bf[32000,512]^T + b ----------------
__global__ __launch_bounds__(256) void k_gemm(
    const ushort_t* __restrict__ A, const ushort_t* __restrict__ Bw,
    const float* __restrict__ bias, float* __restrict__ C)
{
  __shared__ ushort_t As[128 * 64];
  __shared__ ushort_t Bs[128 * 64];
  const int tid = threadIdx.x;
  const int wave = tid >> 6, lane = tid & 63;
  const int ln = lane & 15, quad = lane >> 4;
  const int bm = blockIdx.x & 15, bn = blockIdx.x >> 4;
  const int wm = wave & 1, wn = wave >> 1;

  f32x4 acc[4][4];
#pragma unroll
  for (int i = 0; i < 4; i++)
#pragma unroll
    for (int j = 0; j < 4; j++) { acc[i][j][0] = 0.f; acc[i][j][1] = 0.f; acc[i][j][2] = 0.f; acc[i][j][3] = 0.f; }

  for (int kt = 0; kt < 8; kt++) {
    const int k0 = kt * 64;
#pragma unroll
    for (int i = 0; i < 4; i++) {
      int s = i * 256 + tid;
      int r = s >> 3, c = s & 7;
      int cs = c ^ (r & 7);
      async_g2l(A + ((size_t)(bm * 128 + r) << 9) + k0 + (cs << 3), &As[s << 3]);
    }
#pragma unroll
    for (int i = 0; i < 4; i++) {
      int s = i * 256 + tid;
      int r = s >> 3, c = s & 7;
      int cs = c ^ (r & 7);
      async_g2l(Bw + ((size_t)(bn * 128 + r) << 9) + k0 + (cs << 3), &Bs[s << 3]);
    }
    __syncthreads();
#pragma unroll
    for (int ks = 0; ks < 2; ks++) {
      bf16x8 af[4], bfr[4];
      int cc = ks * 4 + quad;
#pragma unroll
      for (int f = 0; f < 4; f++) {
        int ra = wm * 64 + f * 16 + ln;
        af[f] = *(const bf16x8*)&As[((ra << 3) + (cc ^ (ra & 7))) << 3];
        int rb = wn * 64 + f * 16 + ln;
        bfr[f] = *(const bf16x8*)&Bs[((rb << 3) + (cc ^ (rb & 7))) << 3];
      }
#pragma unroll
      for (int mf = 0; mf < 4; mf++)
#pragma unroll
        for (int nf = 0; nf < 4; nf++)
          acc[mf][nf] = __builtin_amdgcn_mfma_f32_16x16x32_bf16(af[mf], bfr[nf], acc[mf][nf], 0, 0, 0);
    }
    __syncthreads();
  }
#pragma unroll
  for (int nf = 0; nf < 4; nf++) {
    int n = bn * 128 + wn * 64 + nf * 16 + ln;
    float bv = bias[n];
#pragma unroll
    for (int mf = 0; mf < 4; mf++) {
      int mbase = bm * 128 + wm * 64 + mf * 16 + (quad << 2);
#pragma unroll
      for (int r = 0; r < 4; r++)
        C[(size_t)(mbase + r) * 32000 + n] = acc[mf][nf][r] + bv;
    }
  }
}

// ---------------- launch ----------------
extern "C" void kernel_launch(void* const* d_in, const int* in_sizes, int n_in,
                              void* d_out, int out_size, void* d_ws, size_t ws_size,
                              hipStream_t stream) {
  const float* word  = (const float*)d_in[0];
  const float* sent  = (const float*)d_in[1];
  const float* W2    = (const float*)d_in[2];
  const float* W4    = (const float*)d_in[3];
  const float* W_ih  = (const float*)d_in[4];
  const float* W_hh  = (const float*)d_in[5];
  const float* b_ih  = (const float*)d_in[6];
  const float* b_hh  = (const float*)d_in[7];
  const float* W_out = (const float*)d_in[8];
  const float* b_out = (const float*)d_in[9];
  float* out = (float*)d_out;

  char* ws = (char*)d_ws;
  unsigned* hflag   = (unsigned*)(ws + 0);          // [128]
  unsigned* xflag   = (unsigned*)(ws + 512);        // [32]
  ull_t*    hbuf    = (ull_t*)(ws + 1024);          // 2 x [32][512] bf16 (parity)
  ull_t*    xbuf    = (ull_t*)(ws + 66560);         // [32][512] bf16
  float*    sp      = (float*)(ws + 99328);         // [32][512] fp32
  ushort_t* P       = (ushort_t*)(ws + 164864);     // [32][128][512] bf16
  ushort_t* w_bf    = (ushort_t*)(ws + 4359168);    // [32][128][512] bf16 (pre-scaled x2)
  ull_t*    h_A     = (ull_t*)(ws + 8553472);       // [2048][512] bf16 (m = b*64+t)
  ushort_t* Wout_bf = (ushort_t*)(ws + 10650624);   // [32000][512] bf16 -> ends 43,418,624
  float* h_fin = out + 65536000;

  hipMemsetAsync(ws, 0, 66560, stream);             // zero flags + both h parity buffers

  k_f2bf<<<2048, 256, 0, stream>>>(W_out, Wout_bf, 16384000 / 4, 1.0f);
  k_f2bf<<<512, 256, 0, stream>>>(word, w_bf, 2097152 / 4, 2.0f);   // x2: exact in bf16
  k_initP<<<dim3(65, 8), 256, 0, stream>>>(word, sent, W4, P, sp);
  k_recur<<<160, 512, 0, stream>>>(W2, W_ih, W_hh, b_ih, b_hh, w_bf, P, sp,
                                   hflag, xflag, hbuf, xbuf, h_A, h_fin);
  k_gemm<<<4000, 256, 0, stream>>>((const ushort_t*)h_A, Wout_bf, b_out, out);
}

// Round 6
// 1508.237 us; speedup vs baseline: 1.1959x; 1.0465x over previous
//
#include <hip/hip_runtime.h>
#include <stdint.h>

typedef unsigned short ushort_t;
typedef unsigned long long ull_t;
typedef __attribute__((ext_vector_type(8))) short bf16x8;
typedef __attribute__((ext_vector_type(8))) unsigned short u16x8;
typedef __attribute__((ext_vector_type(4))) unsigned short u16x4;
typedef __attribute__((ext_vector_type(4))) float f32x4;
typedef __attribute__((ext_vector_type(4))) unsigned u32x4;

#define DEV static __device__ __forceinline__
#define SCOPE_AGENT __HIP_MEMORY_SCOPE_AGENT

DEV unsigned short f2bf(float f) {           // fp32 -> bf16 RNE
  unsigned u = __float_as_uint(f);
  u += 0x7FFFu + ((u >> 16) & 1u);
  return (unsigned short)(u >> 16);
}
DEV float bf2f(unsigned short h) { return __uint_as_float(((unsigned)h) << 16); }
DEV float fast_rcp(float x) { return __builtin_amdgcn_rcpf(x); }
DEV float fast_tanh(float x) { float e = __expf(2.f * x); return (e - 1.f) * fast_rcp(e + 1.f); }
DEV float fast_sigm(float x) { return fast_rcp(1.f + __expf(-x)); }

DEV float wave_sum(float v) {
#pragma unroll
  for (int d = 32; d > 0; d >>= 1) v += __shfl_xor(v, d, 64);
  return v;
}
DEV float wave_max(float v) {
#pragma unroll
  for (int d = 32; d > 0; d >>= 1) v = fmaxf(v, __shfl_xor(v, d, 64));
  return v;
}

DEV void async_g2l(const void* g, void* l) {   // 16B global -> LDS (dest = uniform base + lane*16)
  __builtin_amdgcn_global_load_lds((const __attribute__((address_space(1))) void*)g,
                                   (__attribute__((address_space(3))) void*)l, 16, 0, 0);
}

// ---- scoped-atomic communication helpers (publish side: round-0/5-proven protocol) ----
DEV unsigned ld_flag(unsigned* p) { return __hip_atomic_load(p, __ATOMIC_RELAXED, SCOPE_AGENT); }
DEV void st_flag(unsigned* p, unsigned v) { __hip_atomic_store(p, v, __ATOMIC_RELAXED, SCOPE_AGENT); }
DEV void st_u64(ull_t* p, ull_t v) { __hip_atomic_store(p, v, __ATOMIC_RELAXED, SCOPE_AGENT); }
DEV void release_fence() { __builtin_amdgcn_s_waitcnt(0); }   // drain vm+lgkm: prior stores visible

// ---- consumer side: coherent (L1/L2-bypass) COALESCING plain loads ----
// Unlike per-lane atomics, a wave's lanes reading one 64B segment collapse into a single
// fabric transaction. Load path proven correct vs atomic publishes in rounds 1 and 4.
DEV u32x4 ld_coh16(const void* p) {
  u32x4 v;
  asm volatile("global_load_dwordx4 %0, %1, off sc0 sc1" : "=v"(v) : "v"(p));
  return v;
}
DEV unsigned ld_coh4(const unsigned* p) {
  unsigned v;
  asm volatile("global_load_dword %0, %1, off sc0 sc1" : "=v"(v) : "v"(p));
  return v;
}
DEV void wait_vm0() { asm volatile("s_waitcnt vmcnt(0)" ::: "memory"); }

// ---------------- fp32 -> bf16 bulk convert with scale (float4 at a time) ----------------
__global__ void k_f2bf(const float* __restrict__ in, ushort_t* __restrict__ out, int n4, float scale) {
  int i = blockIdx.x * blockDim.x + threadIdx.x;
  int st = gridDim.x * blockDim.x;
  for (; i < n4; i += st) {
    f32x4 v = *(const f32x4*)(in + (size_t)i * 4);
    u16x4 o;
    o[0] = f2bf(v[0] * scale); o[1] = f2bf(v[1] * scale);
    o[2] = f2bf(v[2] * scale); o[3] = f2bf(v[3] * scale);
    *(u16x4*)(out + (size_t)i * 4) = o;
  }
}

// ---------------- init GEMM (fp32 vector): P[m,r] = A'[m,:]·W4[r,512+:] (bf16 out) ----------------
__global__ __launch_bounds__(256) void k_initP(
    const float* __restrict__ w, const float* __restrict__ sent,
    const float* __restrict__ W4, ushort_t* __restrict__ P, float* __restrict__ sp)
{
  __shared__ float As2[16 * 68];
  __shared__ float Bs2[16 * 68];
  const int tid = threadIdx.x;
  const int m0 = blockIdx.x * 64, n0 = blockIdx.y * 64;
  const int tm = tid & 15, tn = tid >> 4;
  const bool sent_half = (m0 >= 4096);
  float acc[4][4];
#pragma unroll
  for (int i = 0; i < 4; i++)
#pragma unroll
    for (int j = 0; j < 4; j++) acc[i][j] = 0.f;

  for (int k0 = 0; k0 < 512; k0 += 16) {
#pragma unroll
    for (int i = 0; i < 4; i++) {
      int idx = i * 256 + tid;
      int r = idx >> 4, kk = idx & 15;
      int m = m0 + r;
      float va = 0.f;
      if (m < 4096) va = w[(size_t)m * 512 + k0 + kk];
      else if (m < 4128) va = sent[(m - 4096) * 512 + k0 + kk];
      As2[kk * 68 + r] = va;
      Bs2[kk * 68 + r] = W4[(size_t)(n0 + r) * 1024 + (sent_half ? 0 : 512) + k0 + kk];
    }
    __syncthreads();
#pragma unroll
    for (int k = 0; k < 16; k++) {
      f32x4 av = *(const f32x4*)&As2[k * 68 + tm * 4];
      f32x4 bv = *(const f32x4*)&Bs2[k * 68 + tn * 4];
#pragma unroll
      for (int i = 0; i < 4; i++)
#pragma unroll
        for (int j = 0; j < 4; j++) acc[i][j] = fmaf(av[i], bv[j], acc[i][j]);
    }
    __syncthreads();
  }
#pragma unroll
  for (int i = 0; i < 4; i++) {
    int m = m0 + tm * 4 + i;
    if (m >= 4128) continue;
#pragma unroll
    for (int j = 0; j < 4; j++) {
      int n = n0 + tn * 4 + j;
      if (m < 4096) P[(size_t)m * 512 + n] = f2bf(acc[i][j]);
      else sp[(m - 4096) * 512 + n] = acc[i][j];
    }
  }
}

// ---------------- persistent recurrence: 160 blocks x 512 threads (round-5 layout) ----------------
// Blocks 0..127  : gate blocks — own 4 h-rows (16 gate rows), weights persistent in registers.
// Blocks 128..159: attention blocks — one per batch, scores+softmax+x fully block-local.
// This round: ALL hot-loop consumer reads (h/x staging + flag polls) converted from per-lane
// 8B atomic loads (~530K serialized LLC transactions/step) to wave-coalesced plain sc0+sc1
// vector loads (~33K transactions/step). Publishes stay per-lane atomic (proven protocol).
struct GateS {
  ushort_t XHx[32 * 520];     // staged [batch][k] bf16, padded
  float gredf[8 * 512];       // per-wave MFMA partials
  float gates[32 * 17];
  float bias[16];
  float cstate[128];
  ushort_t hs16[128];
};
struct AttnS {
  float hs[512];              // 2*h[t-1] (scores-only)
  float sps[512];
  float scp[128 * 68];        // per-lane score partials, padded rows
  float scp4[512];            // 4-per-s reduced partials
  float attw[128];
  float xpart[8 * 520];
  ushort_t xs16[512];
};

__global__ __launch_bounds__(512) void k_recur(
    const float* __restrict__ W2, const float* __restrict__ W_ih, const float* __restrict__ W_hh,
    const float* __restrict__ b_ih, const float* __restrict__ b_hh,
    const ushort_t* __restrict__ w_bf, const ushort_t* __restrict__ P, const float* __restrict__ sp,
    unsigned* hflag, unsigned* xflag, ull_t* hbuf, ull_t* xbuf,
    ull_t* __restrict__ h_A, float* __restrict__ h_fin)
{
  __shared__ union { GateS g; AttnS a; } sm;
  const int bid = blockIdx.x, tid = threadIdx.x;
  const int wv = tid >> 6, lane = tid & 63;

  // coalesced polls: wave 0 reads the whole flag array in 1-2 64B segments, __all decides.
#define POLLH(TVAL)                                                          \
    for (;;) {                                                               \
      u32x4 f_ = ld_coh16(&hflag[(lane & 31) << 2]);                         \
      wait_vm0();                                                            \
      bool ok_ = f_[0] >= (unsigned)(TVAL) && f_[1] >= (unsigned)(TVAL) &&   \
                 f_[2] >= (unsigned)(TVAL) && f_[3] >= (unsigned)(TVAL);     \
      if (__all((int)ok_)) break;                                            \
      __builtin_amdgcn_s_sleep(2);                                           \
    }
#define POLLX(TVAL)                                                          \
    for (;;) {                                                               \
      unsigned f_ = ld_coh4(&xflag[lane & 31]);                              \
      wait_vm0();                                                            \
      if (__all((int)(f_ >= (unsigned)(TVAL)))) break;                       \
      __builtin_amdgcn_s_sleep(2);                                           \
    }
// coalesced 16B stage of one 32KB buffer (h or x) into XHx: unit u covers u64s 2u,2u+1
#define STAGE_XH(SRC)                                                        \
    {                                                                        \
      const char* src_ = (const char*)(SRC);                                 \
      u32x4 r0 = ld_coh16(src_ + (tid << 4));                                \
      u32x4 r1 = ld_coh16(src_ + ((512 + tid) << 4));                        \
      u32x4 r2 = ld_coh16(src_ + ((1024 + tid) << 4));                       \
      u32x4 r3 = ld_coh16(src_ + ((1536 + tid) << 4));                       \
      wait_vm0();                                                            \
      int c1 = 512 + tid, c2 = 1024 + tid, c3 = 1536 + tid;                  \
      *(u32x4*)&sm.g.XHx[(tid >> 6) * 520 + (tid & 63) * 8] = r0;            \
      *(u32x4*)&sm.g.XHx[(c1 >> 6) * 520 + (c1 & 63) * 8] = r1;              \
      *(u32x4*)&sm.g.XHx[(c2 >> 6) * 520 + (c2 & 63) * 8] = r2;              \
      *(u32x4*)&sm.g.XHx[(c3 >> 6) * 520 + (c3 & 63) * 8] = r3;              \
    }

  if (bid < 128) {
    // ================= gate block =================
    const int n16 = lane & 15, quad = lane >> 4;
    const int grow = (n16 >> 2) * 512 + (bid << 2) + (n16 & 3);
    if (tid < 128) sm.g.cstate[tid] = 0.f;
    if (tid < 16) {
      int gr = (tid >> 2) * 512 + (bid << 2) + (tid & 3);
      sm.g.bias[tid] = b_ih[gr] + b_hh[gr];
    }
    bf16x8 fih[2], fhh[2];
#pragma unroll
    for (int ks = 0; ks < 2; ks++) {
      int kk = (wv * 2 + ks) * 32 + quad * 8;
      const float* pi = W_ih + (size_t)grow * 512 + kk;
      const float* ph = W_hh + (size_t)grow * 512 + kk;
#pragma unroll
      for (int j = 0; j < 8; j++) {
        fih[ks][j] = (short)f2bf(pi[j]);
        fhh[ks][j] = (short)f2bf(ph[j]);
      }
    }
    __syncthreads();

    for (int t = 0; t < 64; t++) {
      // wait h[t-1] published (t=0: hbuf parity 1 is zeroed h0)
      if (t > 0 && wv == 0) { POLLH(t) }
      __syncthreads();
      // stage h[t-1] -> LDS (coalesced coherent 16B loads)
      STAGE_XH(hbuf + ((t + 1) & 1) * 4096)
      __syncthreads();
      f32x4 acc0 = {0.f, 0.f, 0.f, 0.f}, acc1 = {0.f, 0.f, 0.f, 0.f};
#pragma unroll
      for (int ks = 0; ks < 2; ks++) {      // W_hh half — overlaps attention's compute
        int kk = (wv * 2 + ks) * 32 + quad * 8;
        bf16x8 a0 = *(const bf16x8*)&sm.g.XHx[n16 * 520 + kk];
        bf16x8 a1 = *(const bf16x8*)&sm.g.XHx[(16 + n16) * 520 + kk];
        acc0 = __builtin_amdgcn_mfma_f32_16x16x32_bf16(a0, fhh[ks], acc0, 0, 0, 0);
        acc1 = __builtin_amdgcn_mfma_f32_16x16x32_bf16(a1, fhh[ks], acc1, 0, 0, 0);
      }
      // wait x[t]
      if (wv == 0) { POLLX(t + 1) }
      __syncthreads();
      STAGE_XH(xbuf)
      __syncthreads();
#pragma unroll
      for (int ks = 0; ks < 2; ks++) {      // W_ih half
        int kk = (wv * 2 + ks) * 32 + quad * 8;
        bf16x8 a0 = *(const bf16x8*)&sm.g.XHx[n16 * 520 + kk];
        bf16x8 a1 = *(const bf16x8*)&sm.g.XHx[(16 + n16) * 520 + kk];
        acc0 = __builtin_amdgcn_mfma_f32_16x16x32_bf16(a0, fih[ks], acc0, 0, 0, 0);
        acc1 = __builtin_amdgcn_mfma_f32_16x16x32_bf16(a1, fih[ks], acc1, 0, 0, 0);
      }
      *(f32x4*)&sm.g.gredf[wv * 512 + lane * 4] = acc0;
      *(f32x4*)&sm.g.gredf[wv * 512 + 256 + lane * 4] = acc1;
      __syncthreads();
      {
        float v = 0.f;
#pragma unroll
        for (int k = 0; k < 8; k++) v += sm.g.gredf[k * 512 + tid];
        int mt = tid >> 8, l = (tid >> 2) & 63, r = tid & 3;
        int batch = mt * 16 + ((l >> 4) << 2) + r;   // C/D: row=(lane>>4)*4+reg, col=lane&15
        int n = l & 15;
        sm.g.gates[batch * 17 + n] = v + sm.g.bias[n];
      }
      __syncthreads();
      if (tid < 128) {
        int bb = tid & 31, hr = tid >> 5;
        float gi = sm.g.gates[bb * 17 + hr];
        float gf = sm.g.gates[bb * 17 + 4 + hr];
        float gg = sm.g.gates[bb * 17 + 8 + hr];
        float go = sm.g.gates[bb * 17 + 12 + hr];
        float cold = sm.g.cstate[(bb << 2) + hr];
        float cn = fast_sigm(gf) * cold + fast_sigm(gi) * fast_tanh(gg);
        float hn = fast_sigm(go) * fast_tanh(cn);
        sm.g.cstate[(bb << 2) + hr] = cn;
        sm.g.hs16[(bb << 2) + hr] = f2bf(hn);
        if (t == 63) h_fin[bb * 512 + (bid << 2) + hr] = hn;
      }
      __syncthreads();
      if (tid < 32) {
        ull_t v = *(const ull_t*)&sm.g.hs16[tid << 2];
        st_u64(&hbuf[(t & 1) * 4096 + tid * 128 + bid], v);   // h[t], parity-buffered
        h_A[((tid << 6) + t) * 128 + bid] = v;                // GEMM A row m=b*64+t (plain store)
        release_fence();
      }
      __syncthreads();
      if (tid == 0) st_flag(&hflag[bid], (unsigned)(t + 1));
    }
  } else {
    // ================= attention block (batch b) =================
    const int b = bid - 128;
    float w2v[8];
#pragma unroll
    for (int j = 0; j < 8; j++) w2v[j] = W2[lane * 8 + j];
    float sumW2;
    {
      float sw = 0.f;
#pragma unroll
      for (int j = 0; j < 8; j++) sw += w2v[j];
      sumW2 = wave_sum(sw);              // every wave covers all 512 k
    }
    sm.a.sps[tid] = sp[b * 512 + tid];
    __syncthreads();

    for (int t = 0; t < 64; t++) {
      if (t > 0 && wv == 0) { POLLH(t) }
      __syncthreads();
      if (tid < 64) {                    // stage 2*h[t-1] (coalesced coherent 16B loads)
        u32x4 hv = ld_coh16((const char*)hbuf + (((t + 1) & 1) << 15) + (b << 10) + (tid << 4));
        wait_vm0();
#pragma unroll
        for (int j = 0; j < 4; j++) {
          sm.a.hs[tid * 8 + 2 * j]     = 2.f * bf2f((ushort_t)(hv[j] & 0xffffu));
          sm.a.hs[tid * 8 + 2 * j + 1] = 2.f * bf2f((ushort_t)(hv[j] >> 16));
        }
      }
      __syncthreads();
      // scores: tanh(w+h)·W2 = SumW2 - 2*Sum W2/(1+e^{2(w+h)}); w_bf pre-scaled by 2
      float hf[8];
#pragma unroll
      for (int j = 0; j < 8; j++) hf[j] = sm.a.hs[lane * 8 + j];
#pragma unroll 4
      for (int i = 0; i < 16; i++) {
        int s = (wv << 4) + i;
        u16x8 wvv = *(const u16x8*)(w_bf + ((size_t)((b << 7) + s) << 9) + (lane << 3));
        float p = 0.f;
#pragma unroll
        for (int j = 0; j < 8; j++) {
          float v = bf2f(wvv[j]) + hf[j];        // = 2*(w+h)
          float e = __expf(v);
          p = fmaf(w2v[j], fast_rcp(1.f + e), p);
        }
        sm.a.scp[s * 68 + lane] = p;             // per-lane partial (no wave_sum chain)
      }
      __syncthreads();
      {                                          // reduce 64 partials -> 4 per s
        int s = tid >> 2, q = tid & 3;
        const float* pp = &sm.a.scp[s * 68 + q * 16];
        float r = 0.f;
#pragma unroll
        for (int m = 0; m < 16; m++) r += pp[m];
        sm.a.scp4[tid] = r;
      }
      __syncthreads();
      if (wv == 0) {   // finalize scores + softmax (wave 0)
        f32x4 p0 = *(const f32x4*)&sm.a.scp4[lane * 4];
        f32x4 p1 = *(const f32x4*)&sm.a.scp4[256 + lane * 4];
        float a0 = sumW2 - 2.f * (p0[0] + p0[1] + p0[2] + p0[3]);
        float a1 = sumW2 - 2.f * (p1[0] + p1[1] + p1[2] + p1[3]);
        float m = wave_max(fmaxf(a0, a1));
        float e0 = __expf(a0 - m), e1 = __expf(a1 - m);
        float inv = fast_rcp(wave_sum(e0 + e1));
        sm.a.attw[lane] = e0 * inv;
        sm.a.attw[lane + 64] = e1 * inv;
      }
      __syncthreads();
      // x = tanh(sp + attn·P): wave wv handles s in [wv*16, wv*16+16), lane owns r = lane*8..+8
      {
        f32x4 xacc0 = {0.f, 0.f, 0.f, 0.f}, xacc1 = {0.f, 0.f, 0.f, 0.f};
        const ushort_t* Pb = P + (((size_t)b * 128 + (wv << 4)) << 9) + lane * 8;
#pragma unroll 4
        for (int i = 0; i < 16; i++) {
          float aw = sm.a.attw[(wv << 4) + i];
          u16x8 pv = *(const u16x8*)(Pb + ((size_t)i << 9));
#pragma unroll
          for (int j = 0; j < 4; j++) xacc0[j] = fmaf(aw, bf2f(pv[j]), xacc0[j]);
#pragma unroll
          for (int j = 0; j < 4; j++) xacc1[j] = fmaf(aw, bf2f(pv[4 + j]), xacc1[j]);
        }
        *(f32x4*)&sm.a.xpart[wv * 520 + lane * 8] = xacc0;
        *(f32x4*)&sm.a.xpart[wv * 520 + lane * 8 + 4] = xacc1;
      }
      __syncthreads();
      {
        float xv = sm.a.sps[tid];
#pragma unroll
        for (int g = 0; g < 8; g++) xv += sm.a.xpart[g * 520 + tid];
        sm.a.xs16[tid] = f2bf(fast_tanh(xv));
      }
      __syncthreads();
      if (tid < 128) {
        ull_t v = *(const ull_t*)&sm.a.xs16[tid << 2];
        st_u64(&xbuf[(b << 7) + tid], v);
        release_fence();
      }
      __syncthreads();
      if (tid == 0) st_flag(&xflag[b], (unsigned)(t + 1));
    }
  }
#undef POLLH
#undef POLLX
#undef STAGE_XH
}

// ---------------- big GEMM: C[2048,32000] = h_A[2048,512] x W_out_bf[32000,512]^T + b ----------------
__global__ __launch_bounds__(256) void k_gemm(
    const ushort_t* __restrict__ A, const ushort_t* __restrict__ Bw,
    const float* __restrict__ bias, float* __restrict__ C)
{
  __shared__ ushort_t As[128 * 64];
  __shared__ ushort_t Bs[128 * 64];
  const int tid = threadIdx.x;
  const int wave = tid >> 6, lane = tid & 63;
  const int ln = lane & 15, quad = lane >> 4;
  const int bm = blockIdx.x & 15, bn = blockIdx.x >> 4;
  const int wm = wave & 1, wn = wave >> 1;

  f32x4 acc[4][4];
#pragma unroll
  for (int i = 0; i < 4; i++)
#pragma unroll
    for (int j = 0; j < 4; j++) { acc[i][j][0] = 0.f; acc[i][j][1] = 0.f; acc[i][j][2] = 0.f; acc[i][j][3] = 0.f; }

  for (int kt = 0; kt < 8; kt++) {
    const int k0 = kt * 64;
#pragma unroll
    for (int i = 0; i < 4; i++) {
      int s = i * 256 + tid;
      int r = s >> 3, c = s & 7;
      int cs = c ^ (r & 7);
      async_g2l(A + ((size_t)(bm * 128 + r) << 9) + k0 + (cs << 3), &As[s << 3]);
    }
#pragma unroll
    for (int i = 0; i < 4; i++) {
      int s = i * 256 + tid;
      int r = s >> 3, c = s & 7;
      int cs = c ^ (r & 7);
      async_g2l(Bw + ((size_t)(bn * 128 + r) << 9) + k0 + (cs << 3), &Bs[s << 3]);
    }
    __syncthreads();
#pragma unroll
    for (int ks = 0; ks < 2; ks++) {
      bf16x8 af[4], bfr[4];
      int cc = ks * 4 + quad;
#pragma unroll
      for (int f = 0; f < 4; f++) {
        int ra = wm * 64 + f * 16 + ln;
        af[f] = *(const bf16x8*)&As[((ra << 3) + (cc ^ (ra & 7))) << 3];
        int rb = wn * 64 + f * 16 + ln;
        bfr[f] = *(const bf16x8*)&Bs[((rb << 3) + (cc ^ (rb & 7))) << 3];
      }
#pragma unroll
      for (int mf = 0; mf < 4; mf++)
#pragma unroll
        for (int nf = 0; nf < 4; nf++)
          acc[mf][nf] = __builtin_amdgcn_mfma_f32_16x16x32_bf16(af[mf], bfr[nf], acc[mf][nf], 0, 0, 0);
    }
    __syncthreads();
  }
#pragma unroll
  for (int nf = 0; nf < 4; nf++) {
    int n = bn * 128 + wn * 64 + nf * 16 + ln;
    float bv = bias[n];
#pragma unroll
    for (int mf = 0; mf < 4; mf++) {
      int mbase = bm * 128 + wm * 64 + mf * 16 + (quad << 2);
#pragma unroll
      for (int r = 0; r < 4; r++)
        C[(size_t)(mbase + r) * 32000 + n] = acc[mf][nf][r] + bv;
    }
  }
}

// ---------------- launch ----------------
extern "C" void kernel_launch(void* const* d_in, const int* in_sizes, int n_in,
                              void* d_out, int out_size, void* d_ws, size_t ws_size,
                              hipStream_t stream) {
  const float* word  = (const float*)d_in[0];
  const float* sent  = (const float*)d_in[1];
  const float* W2    = (const float*)d_in[2];
  const float* W4    = (const float*)d_in[3];
  const float* W_ih  = (const float*)d_in[4];
  const float* W_hh  = (const float*)d_in[5];
  const float* b_ih  = (const float*)d_in[6];
  const float* b_hh  = (const float*)d_in[7];
  const float* W_out = (const float*)d_in[8];
  const float* b_out = (const float*)d_in[9];
  float* out = (float*)d_out;

  char* ws = (char*)d_ws;
  unsigned* hflag   = (unsigned*)(ws + 0);          // [128]
  unsigned* xflag   = (unsigned*)(ws + 512);        // [32]
  ull_t*    hbuf    = (ull_t*)(ws + 1024);          // 2 x [32][512] bf16 (parity)
  ull_t*    xbuf    = (ull_t*)(ws + 66560);         // [32][512] bf16
  float*    sp      = (float*)(ws + 99328);         // [32][512] fp32
  ushort_t* P       = (ushort_t*)(ws + 164864);     // [32][128][512] bf16
  ushort_t* w_bf    = (ushort_t*)(ws + 4359168);    // [32][128][512] bf16 (pre-scaled x2)
  ull_t*    h_A     = (ull_t*)(ws + 8553472);       // [2048][512] bf16 (m = b*64+t)
  ushort_t* Wout_bf = (ushort_t*)(ws + 10650624);   // [32000][512] bf16 -> ends 43,418,624
  float* h_fin = out + 65536000;

  hipMemsetAsync(ws, 0, 66560, stream);             // zero flags + both h parity buffers

  k_f2bf<<<2048, 256, 0, stream>>>(W_out, Wout_bf, 16384000 / 4, 1.0f);
  k_f2bf<<<512, 256, 0, stream>>>(word, w_bf, 2097152 / 4, 2.0f);   // x2: exact in bf16
  k_initP<<<dim3(65, 8), 256, 0, stream>>>(word, sent, W4, P, sp);
  k_recur<<<160, 512, 0, stream>>>(W2, W_ih, W_hh, b_ih, b_hh, w_bf, P, sp,
                                   hflag, xflag, hbuf, xbuf, h_A, h_fin);
  k_gemm<<<4000, 256, 0, stream>>>((const ushort_t*)h_A, Wout_bf, b_out, out);
}